// Round 8
// baseline (919.980 us; speedup 1.0000x reference)
//
#include <hip/hip_runtime.h>

// WaveNet residual stack — bf16 MFMA, round 8.
// Single fused per-layer kernel: dilated conv (MFMA) + gate + res (MFMA)
// + skip (MFMA, fp32 global RMW). No skip_gemm, no g staging to global:
// the 63 MB fp32 skip accumulator is re-touched every ~25 µs with <256 MB
// of intervening traffic -> L3-resident RMW (r6/r7 evidence: deferred g was
// L3-evicted and streamed cold at 1.4-1.8 TB/s; locality > pipelining here).
// MFMA layouts (HW-verified): A[m=lane&15][k=quad*8+j], B[k=quad*8+j][n=lane&15],
// C/D col=lane&15 row=quad*4+reg.

#define NBATCH 16
#define C 64
#define SC 128
#define L0 8192
#define OSIZE 7682
#define TILE 64

typedef __bf16 bf16x8 __attribute__((ext_vector_type(8)));
typedef __bf16 bf16x4 __attribute__((ext_vector_type(4)));
typedef float  f32x4  __attribute__((ext_vector_type(4)));

// ---- pre-pass: pack weights to bf16, k-contiguous MFMA A-layout ----
__global__ __launch_bounds__(256) void pack_weights(
    const float* __restrict__ Wd, const float* __restrict__ Wr,
    const float* __restrict__ Ws,
    __bf16* __restrict__ Wdm, __bf16* __restrict__ Wrm, __bf16* __restrict__ Wsm)
{
    int idx = blockIdx.x * 256 + threadIdx.x;
    if (idx < 131072) {                       // Wdm[ly][o][kp]: kp<64 tap0, else tap1
        int kp = idx & 127, o = (idx >> 7) & 63, ly = idx >> 13;
        int k = kp & 63, tap = kp >> 6;
        Wdm[idx] = (__bf16)Wd[(((ly * 64 + o) * 64 + k) << 1) + tap];
    } else if (idx < 196608) {                // Wrm[ly][o][k]
        int j = idx - 131072;
        Wrm[j] = (__bf16)Wr[j];
    } else if (idx < 327680) {                // Wsm[ly][s][k]
        int j = idx - 196608;
        Wsm[j] = (__bf16)Ws[j];
    }
}

// ---- per-layer: conv(MFMA) + gate + res(MFMA) + skip(MFMA, global RMW) ----
__global__ __launch_bounds__(256) void wavenet_layer_mfma(
    const float* __restrict__ src, int src_stride, int Lin,
    float* __restrict__ dst, int dst_stride,
    const __bf16* __restrict__ Wdm,   // [64][128]
    const __bf16* __restrict__ Wrm,   // [64][64]
    const __bf16* __restrict__ Wsm,   // [128][64]
    float* __restrict__ skip,         // [NBATCH][128][OSIZE]
    int d, int skip_init)
{
    extern __shared__ char smem_raw[];
    const int W    = TILE + d;
    const int Lout = Lin - d;
    const int n  = blockIdx.y;
    const int l0 = blockIdx.x * TILE;
    if (l0 >= Lout) return;
    const int np = min(TILE, Lout - l0);

    __bf16* sxp  = (__bf16*)smem_raw;                          // [8][W][8] k-packed
    float*  sres = (float*)(smem_raw + (size_t)8 * W * 8 * 2); // [64][65] fp32
    __bf16* sgp  = (__bf16*)(sres + 64 * 65);                  // [8][64][8] k-packed

    const int t    = threadIdx.x;
    const int lane = t & 63;
    const int wv   = t >> 6;
    const int q    = lane >> 4;
    const int nn   = lane & 15;

    // ---- stage x: bf16 k-packed (+ fp32 residual window) ----
    for (int item = t; item < 8 * W; item += 256) {
        int kg = item / W;
        int p  = item % W;
        bool inb = (l0 + p) < Lin;
        const float* col = src + (size_t)(n * C + kg * 8) * src_stride + l0 + p;
        float v[8];
        #pragma unroll
        for (int j = 0; j < 8; ++j) v[j] = inb ? col[(size_t)j * src_stride] : 0.f;
        bf16x8 bv;
        #pragma unroll
        for (int j = 0; j < 8; ++j) bv[j] = (__bf16)v[j];
        *(bf16x8*)(sxp + ((size_t)kg * W + p) * 8) = bv;
        int pr = p - d;
        if (pr >= 0 && pr < TILE) {
            #pragma unroll
            for (int j = 0; j < 8; ++j) sres[(kg * 8 + j) * 65 + pr] = v[j];
        }
    }
    __syncthreads();

    // ---- phase 1: y = Wd@[x_l;x_r] (K'=128), gate -> sgp ----
    const __bf16* arow = Wdm + (size_t)(wv * 16 + nn) * 128 + q * 8;
    bf16x8 aW[4];
    #pragma unroll
    for (int ks = 0; ks < 4; ++ks) aW[ks] = *(const bf16x8*)(arow + ks * 32);

    #pragma unroll
    for (int nt = 0; nt < 4; ++nt) {
        int p0 = nt * 16;
        f32x4 acc = {0.f, 0.f, 0.f, 0.f};
        acc = __builtin_amdgcn_mfma_f32_16x16x32_bf16(aW[0],
                *(const bf16x8*)(sxp + ((size_t)(q    ) * W + p0 + nn    ) * 8), acc, 0, 0, 0);
        acc = __builtin_amdgcn_mfma_f32_16x16x32_bf16(aW[1],
                *(const bf16x8*)(sxp + ((size_t)(4 + q) * W + p0 + nn    ) * 8), acc, 0, 0, 0);
        acc = __builtin_amdgcn_mfma_f32_16x16x32_bf16(aW[2],
                *(const bf16x8*)(sxp + ((size_t)(q    ) * W + p0 + nn + d) * 8), acc, 0, 0, 0);
        acc = __builtin_amdgcn_mfma_f32_16x16x32_bf16(aW[3],
                *(const bf16x8*)(sxp + ((size_t)(4 + q) * W + p0 + nn + d) * 8), acc, 0, 0, 0);
        bf16x4 gv;
        #pragma unroll
        for (int r = 0; r < 4; ++r) {
            float y = fminf(fmaxf(acc[r], -20.f), 20.f);
            float u = __expf(y);
            gv[r] = (__bf16)(u * (u - 1.f) / fmaf(u, u, 1.f));
        }
        *(bf16x4*)(sgp + ((size_t)(2 * wv + (q >> 1)) * 64 + p0 + nn) * 8 + (q & 1) * 4) = gv;
    }
    __syncthreads();

    // ---- phase 2a: res = Wr@g + x[:, l+d] (fp32 state from LDS) ----
    const __bf16* rrow = Wrm + (size_t)(wv * 16 + nn) * 64 + q * 8;
    bf16x8 aR0 = *(const bf16x8*)rrow;
    bf16x8 aR1 = *(const bf16x8*)(rrow + 32);
    #pragma unroll
    for (int nt = 0; nt < 4; ++nt) {
        int p0 = nt * 16;
        f32x4 acc = {0.f, 0.f, 0.f, 0.f};
        acc = __builtin_amdgcn_mfma_f32_16x16x32_bf16(aR0,
                *(const bf16x8*)(sgp + ((size_t)(q    ) * 64 + p0 + nn) * 8), acc, 0, 0, 0);
        acc = __builtin_amdgcn_mfma_f32_16x16x32_bf16(aR1,
                *(const bf16x8*)(sgp + ((size_t)(4 + q) * 64 + p0 + nn) * 8), acc, 0, 0, 0);
        if (p0 + nn < np) {
            #pragma unroll
            for (int r = 0; r < 4; ++r) {
                int ch = wv * 16 + q * 4 + r;
                dst[(size_t)(n * C + ch) * dst_stride + l0 + p0 + nn]
                    = acc[r] + sres[ch * 65 + p0 + nn];
            }
        }
    }

    // ---- phase 2b: skip contribution (MFMA) + fp32 global RMW (L3-hot) ----
    const int sbase = Lout - OSIZE;     // skip slot j = l - sbase
    if (l0 + TILE > sbase) {
        // wave wv covers skip rows [wv*32, wv*32+32)
        const __bf16* s0 = Wsm + (size_t)(wv * 32 +      nn) * 64 + q * 8;
        const __bf16* s1 = Wsm + (size_t)(wv * 32 + 16 + nn) * 64 + q * 8;
        bf16x8 aS00 = *(const bf16x8*)s0;
        bf16x8 aS01 = *(const bf16x8*)(s0 + 32);
        bf16x8 aS10 = *(const bf16x8*)s1;
        bf16x8 aS11 = *(const bf16x8*)(s1 + 32);
        #pragma unroll
        for (int nt = 0; nt < 4; ++nt) {
            int p0 = nt * 16;
            bf16x8 b0 = *(const bf16x8*)(sgp + ((size_t)(q    ) * 64 + p0 + nn) * 8);
            bf16x8 b1 = *(const bf16x8*)(sgp + ((size_t)(4 + q) * 64 + p0 + nn) * 8);
            f32x4 a0 = {0.f, 0.f, 0.f, 0.f}, a1 = {0.f, 0.f, 0.f, 0.f};
            a0 = __builtin_amdgcn_mfma_f32_16x16x32_bf16(aS00, b0, a0, 0, 0, 0);
            a0 = __builtin_amdgcn_mfma_f32_16x16x32_bf16(aS01, b1, a0, 0, 0, 0);
            a1 = __builtin_amdgcn_mfma_f32_16x16x32_bf16(aS10, b0, a1, 0, 0, 0);
            a1 = __builtin_amdgcn_mfma_f32_16x16x32_bf16(aS11, b1, a1, 0, 0, 0);
            int l = l0 + p0 + nn;
            if (l >= sbase && l < Lout) {
                size_t j = (size_t)(l - sbase);
                size_t base0 = ((size_t)n * SC + wv * 32 +      q * 4) * OSIZE + j;
                size_t base1 = ((size_t)n * SC + wv * 32 + 16 + q * 4) * OSIZE + j;
                if (skip_init) {
                    #pragma unroll
                    for (int r = 0; r < 4; ++r) {
                        skip[base0 + (size_t)r * OSIZE] = a0[r];
                        skip[base1 + (size_t)r * OSIZE] = a1[r];
                    }
                } else {
                    #pragma unroll
                    for (int r = 0; r < 4; ++r) {
                        skip[base0 + (size_t)r * OSIZE] += a0[r];
                        skip[base1 + (size_t)r * OSIZE] += a1[r];
                    }
                }
            }
        }
    }
}

extern "C" void kernel_launch(void* const* d_in, const int* in_sizes, int n_in,
                              void* d_out, int out_size, void* d_ws, size_t ws_size,
                              hipStream_t stream) {
    const float* x      = (const float*)d_in[0];
    const float* W_dil  = (const float*)d_in[1];
    const float* W_res  = (const float*)d_in[2];
    const float* W_skip = (const float*)d_in[3];

    float* out  = (float*)d_out;                        // [16][64][7682]
    float* skip = out + (size_t)NBATCH * C * OSIZE;     // [16][128][7682]

    float*  bufA = (float*)d_ws;
    float*  bufB = bufA + (size_t)NBATCH * C * L0;
    __bf16* Wdm  = (__bf16*)(bufB + (size_t)NBATCH * C * L0);
    __bf16* Wrm  = Wdm + 16 * 64 * 128;
    __bf16* Wsm  = Wrm + 16 * 64 * 64;

    pack_weights<<<1280, 256, 0, stream>>>(W_dil, W_res, W_skip, Wdm, Wrm, Wsm);

    const float* src = x;
    int src_stride = L0, Lin = L0;
    float* bufs[2] = {bufA, bufB};

    for (int i = 0; i < 16; ++i) {
        int d    = 1 << (i & 7);
        int Lout = Lin - d;
        float* dst;
        int dst_stride;
        if (i == 15) { dst = out;         dst_stride = OSIZE; }
        else         { dst = bufs[i & 1]; dst_stride = L0;    }

        int W = TILE + d;
        size_t smem = (size_t)128 * W + 64 * 65 * 4 + 8 * 64 * 8 * 2;

        dim3 grid((Lout + TILE - 1) / TILE, NBATCH);
        wavenet_layer_mfma<<<grid, 256, smem, stream>>>(
            src, src_stride, Lin, dst, dst_stride,
            Wdm + (size_t)i * 64 * 128,
            Wrm + (size_t)i * 64 * 64,
            Wsm + (size_t)i * SC * 64,
            skip, d, (i == 0) ? 1 : 0);

        src = dst;
        src_stride = dst_stride;
        Lin = Lout;
    }
}

// Round 9
// 600.268 us; speedup vs baseline: 1.5326x; 1.5326x over previous
//
#include <hip/hip_runtime.h>

// WaveNet residual stack — bf16 MFMA, round 9.
//  - Layer kernels: round-5/7 structure verbatim (64-pos tile, fp32 sres LDS,
//    g slots to workspace) — measured 22 µs/layer.
//  - skip GEMM: r6 LDS-staged 2-barrier loop with ST=128 (was 64): per gi
//    stages 16 KB via global_load_lds(16B) and runs 32 MFMA/wave — 4x better
//    latency amortization per barrier drain. r8 showed fused per-layer skip
//    RMW thrashes L3 (205 MB HBM/dispatch); deferred-G grouping stays.
// MFMA layouts (HW-verified): A[m=lane&15][k=quad*8+j], B[k=quad*8+j][n=lane&15],
// C/D col=lane&15 row=quad*4+reg.

#define NBATCH 16
#define C 64
#define SC 128
#define L0 8192
#define OSIZE 7682
#define TILE 64
#define ST 128

typedef __bf16 bf16x8 __attribute__((ext_vector_type(8)));
typedef __bf16 bf16x4 __attribute__((ext_vector_type(4)));
typedef float  f32x4  __attribute__((ext_vector_type(4)));

// ---- pre-pass: pack weights to bf16, k-contiguous MFMA A-layout ----
__global__ __launch_bounds__(256) void pack_weights(
    const float* __restrict__ Wd, const float* __restrict__ Wr,
    const float* __restrict__ Ws,
    __bf16* __restrict__ Wdm, __bf16* __restrict__ Wrm, __bf16* __restrict__ Wsm)
{
    int idx = blockIdx.x * 256 + threadIdx.x;
    if (idx < 131072) {                       // Wdm[ly][o][kp]: kp<64 tap0, else tap1
        int kp = idx & 127, o = (idx >> 7) & 63, ly = idx >> 13;
        int k = kp & 63, tap = kp >> 6;
        Wdm[idx] = (__bf16)Wd[(((ly * 64 + o) * 64 + k) << 1) + tap];
    } else if (idx < 196608) {                // Wrm[ly][o][k]
        int j = idx - 131072;
        Wrm[j] = (__bf16)Wr[j];
    } else if (idx < 327680) {                // Wsm[ly][s][k]
        int j = idx - 196608;
        Wsm[j] = (__bf16)Ws[j];
    }
}

// ---- per-layer: conv(MFMA) + gate + res(MFMA) + g window out (round-7) ----
__global__ __launch_bounds__(256) void wavenet_layer_mfma(
    const float* __restrict__ src, int src_stride, int Lin,
    float* __restrict__ dst, int dst_stride,
    const __bf16* __restrict__ Wdm,   // [64][128]
    const __bf16* __restrict__ Wrm,   // [64][64]
    __bf16* __restrict__ gout,        // [NBATCH][8][OSIZE][8] this layer's slot
    int d)
{
    extern __shared__ char smem_raw[];
    const int W    = TILE + d;
    const int Lout = Lin - d;
    const int n  = blockIdx.y;
    const int l0 = blockIdx.x * TILE;
    if (l0 >= Lout) return;
    const int np = min(TILE, Lout - l0);

    __bf16* sxp  = (__bf16*)smem_raw;                          // [8][W][8] k-packed
    float*  sres = (float*)(smem_raw + (size_t)8 * W * 8 * 2); // [64][65] fp32
    __bf16* sgp  = (__bf16*)(sres + 64 * 65);                  // [8][64][8] k-packed

    const int t    = threadIdx.x;
    const int lane = t & 63;
    const int wv   = t >> 6;
    const int q    = lane >> 4;
    const int nn   = lane & 15;

    // ---- stage x: bf16 k-packed (+ fp32 residual window) ----
    for (int item = t; item < 8 * W; item += 256) {
        int kg = item / W;
        int p  = item % W;
        bool inb = (l0 + p) < Lin;
        const float* col = src + (size_t)(n * C + kg * 8) * src_stride + l0 + p;
        float v[8];
        #pragma unroll
        for (int j = 0; j < 8; ++j) v[j] = inb ? col[(size_t)j * src_stride] : 0.f;
        bf16x8 bv;
        #pragma unroll
        for (int j = 0; j < 8; ++j) bv[j] = (__bf16)v[j];
        *(bf16x8*)(sxp + ((size_t)kg * W + p) * 8) = bv;
        int pr = p - d;
        if (pr >= 0 && pr < TILE) {
            #pragma unroll
            for (int j = 0; j < 8; ++j) sres[(kg * 8 + j) * 65 + pr] = v[j];
        }
    }
    __syncthreads();

    // ---- phase 1: y = Wd@[x_l;x_r] (K'=128), gate -> sgp ----
    const __bf16* arow = Wdm + (size_t)(wv * 16 + nn) * 128 + q * 8;
    bf16x8 aW[4];
    #pragma unroll
    for (int ks = 0; ks < 4; ++ks) aW[ks] = *(const bf16x8*)(arow + ks * 32);

    #pragma unroll
    for (int nt = 0; nt < 4; ++nt) {
        int p0 = nt * 16;
        f32x4 acc = {0.f, 0.f, 0.f, 0.f};
        acc = __builtin_amdgcn_mfma_f32_16x16x32_bf16(aW[0],
                *(const bf16x8*)(sxp + ((size_t)(q    ) * W + p0 + nn    ) * 8), acc, 0, 0, 0);
        acc = __builtin_amdgcn_mfma_f32_16x16x32_bf16(aW[1],
                *(const bf16x8*)(sxp + ((size_t)(4 + q) * W + p0 + nn    ) * 8), acc, 0, 0, 0);
        acc = __builtin_amdgcn_mfma_f32_16x16x32_bf16(aW[2],
                *(const bf16x8*)(sxp + ((size_t)(q    ) * W + p0 + nn + d) * 8), acc, 0, 0, 0);
        acc = __builtin_amdgcn_mfma_f32_16x16x32_bf16(aW[3],
                *(const bf16x8*)(sxp + ((size_t)(4 + q) * W + p0 + nn + d) * 8), acc, 0, 0, 0);
        bf16x4 gv;
        #pragma unroll
        for (int r = 0; r < 4; ++r) {
            float y = fminf(fmaxf(acc[r], -20.f), 20.f);
            float u = __expf(y);
            gv[r] = (__bf16)(u * (u - 1.f) / fmaf(u, u, 1.f));
        }
        *(bf16x4*)(sgp + ((size_t)(2 * wv + (q >> 1)) * 64 + p0 + nn) * 8 + (q & 1) * 4) = gv;
    }
    __syncthreads();

    // ---- phase 2a: res = Wr@g + x[:, l+d] (fp32 state from LDS) ----
    const __bf16* rrow = Wrm + (size_t)(wv * 16 + nn) * 64 + q * 8;
    bf16x8 aR0 = *(const bf16x8*)rrow;
    bf16x8 aR1 = *(const bf16x8*)(rrow + 32);
    #pragma unroll
    for (int nt = 0; nt < 4; ++nt) {
        int p0 = nt * 16;
        f32x4 acc = {0.f, 0.f, 0.f, 0.f};
        acc = __builtin_amdgcn_mfma_f32_16x16x32_bf16(aR0,
                *(const bf16x8*)(sgp + ((size_t)(q    ) * 64 + p0 + nn) * 8), acc, 0, 0, 0);
        acc = __builtin_amdgcn_mfma_f32_16x16x32_bf16(aR1,
                *(const bf16x8*)(sgp + ((size_t)(4 + q) * 64 + p0 + nn) * 8), acc, 0, 0, 0);
        if (p0 + nn < np) {
            #pragma unroll
            for (int r = 0; r < 4; ++r) {
                int ch = wv * 16 + q * 4 + r;
                dst[(size_t)(n * C + ch) * dst_stride + l0 + p0 + nn]
                    = acc[r] + sres[ch * 65 + p0 + nn];
            }
        }
    }

    // ---- write g window (bf16, b128 coalesced) ----
    const int sbase = Lout - OSIZE;
    for (int item = t; item < 8 * TILE; item += 256) {
        int p  = item & 63;
        int kg = item >> 6;
        int l  = l0 + p;
        if (l >= sbase && l < Lout) {
            *(bf16x8*)(gout + (((size_t)n * 8 + kg) * OSIZE + (l - sbase)) * 8)
                = *(const bf16x8*)(sgp + ((size_t)kg * 64 + p) * 8);
        }
    }
}

// ---- skip = sum over G layers of Ws@g ; LDS-staged, ST=128 ----
__global__ __launch_bounds__(256) void skip_gemm(
    const __bf16* __restrict__ g,     // [G][NBATCH][8][OSIZE][8]
    const __bf16* __restrict__ Wsm,   // [16][128][64]
    float* __restrict__ skip,         // [NBATCH][128][OSIZE]
    int G, int lybase, int init)
{
    __shared__ __bf16 Bb[8][ST][8];   // 16 KB B-tile
    const int n  = blockIdx.y;
    const int l0 = blockIdx.x * ST;
    const int t  = threadIdx.x;
    const int lane = t & 63;
    const int wv   = __builtin_amdgcn_readfirstlane(t >> 6);
    const int q = lane >> 4, nn = lane & 15;

    f32x4 acc[2][8];
    #pragma unroll
    for (int mt = 0; mt < 2; ++mt)
        #pragma unroll
        for (int nt = 0; nt < 8; ++nt) acc[mt][nt] = (f32x4){0.f, 0.f, 0.f, 0.f};

    for (int gi = 0; gi < G; ++gi) {
        // stage B-tile: 16 KB, 16 instrs (4/wave), each 64 lanes x 16B contiguous
        const __bf16* gl = g + ((size_t)gi * NBATCH + n) * (size_t)8 * OSIZE * 8;
        #pragma unroll
        for (int j = 0; j < 4; ++j) {
            int kg   = 2 * wv + (j >> 1);
            int half = j & 1;
            const __bf16* srcp = gl + ((size_t)kg * OSIZE + l0 + half * 64) * 8
                                    + (size_t)lane * 8;
            __builtin_amdgcn_global_load_lds(
                (const __attribute__((address_space(1))) void*)srcp,
                (__attribute__((address_space(3))) void*)&Bb[kg][half * 64][0],
                16, 0, 0);
        }
        // A-frags (L2-hot after first block)
        const __bf16* Wl = Wsm + (size_t)(lybase + gi) * SC * 64;
        bf16x8 a00 = *(const bf16x8*)(Wl + (size_t)(wv * 32 +      nn) * 64 +  0 + q * 8);
        bf16x8 a01 = *(const bf16x8*)(Wl + (size_t)(wv * 32 +      nn) * 64 + 32 + q * 8);
        bf16x8 a10 = *(const bf16x8*)(Wl + (size_t)(wv * 32 + 16 + nn) * 64 +  0 + q * 8);
        bf16x8 a11 = *(const bf16x8*)(Wl + (size_t)(wv * 32 + 16 + nn) * 64 + 32 + q * 8);
        __syncthreads();              // drain global_load_lds
        #pragma unroll
        for (int ks = 0; ks < 2; ++ks) {
            #pragma unroll
            for (int nt = 0; nt < 8; ++nt) {
                bf16x8 b = *(const bf16x8*)&Bb[ks * 4 + q][nt * 16 + nn][0];
                acc[0][nt] = __builtin_amdgcn_mfma_f32_16x16x32_bf16(
                                 ks ? a01 : a00, b, acc[0][nt], 0, 0, 0);
                acc[1][nt] = __builtin_amdgcn_mfma_f32_16x16x32_bf16(
                                 ks ? a11 : a10, b, acc[1][nt], 0, 0, 0);
            }
        }
        __syncthreads();              // protect Bb before next stage
    }

    #pragma unroll
    for (int mt = 0; mt < 2; ++mt)
        #pragma unroll
        for (int nt = 0; nt < 8; ++nt) {
            int p = l0 + nt * 16 + nn;
            if (p < OSIZE) {
                #pragma unroll
                for (int r = 0; r < 4; ++r) {
                    int s = wv * 32 + mt * 16 + q * 4 + r;
                    size_t idx = ((size_t)n * SC + s) * OSIZE + p;
                    float v = acc[mt][nt][r];
                    skip[idx] = init ? v : (skip[idx] + v);
                }
            }
        }
}

extern "C" void kernel_launch(void* const* d_in, const int* in_sizes, int n_in,
                              void* d_out, int out_size, void* d_ws, size_t ws_size,
                              hipStream_t stream) {
    const float* x      = (const float*)d_in[0];
    const float* W_dil  = (const float*)d_in[1];
    const float* W_res  = (const float*)d_in[2];
    const float* W_skip = (const float*)d_in[3];

    float* out  = (float*)d_out;                        // [16][64][7682]
    float* skip = out + (size_t)NBATCH * C * OSIZE;     // [16][128][7682]

    float*  bufA = (float*)d_ws;
    float*  bufB = bufA + (size_t)NBATCH * C * L0;
    __bf16* Wdm  = (__bf16*)(bufB + (size_t)NBATCH * C * L0);
    __bf16* Wrm  = Wdm + 16 * 64 * 128;
    __bf16* Wsm  = Wrm + 16 * 64 * 64;
    __bf16* gst  = Wsm + 16 * 128 * 64;

    const size_t slotHW = (size_t)NBATCH * 8 * OSIZE * 8;   // halfwords per slot
    const size_t used   = (size_t)((char*)gst - (char*)d_ws);
    int G = 16;
    // 64 KB slack: edge-tile staging reads past the last row (masked at store)
    while (G > 1 && used + (size_t)G * slotHW * 2 + 65536 > ws_size) G >>= 1;

    pack_weights<<<1280, 256, 0, stream>>>(W_dil, W_res, W_skip, Wdm, Wrm, Wsm);

    const float* src = x;
    int src_stride = L0, Lin = L0;
    float* bufs[2] = {bufA, bufB};

    for (int i = 0; i < 16; ++i) {
        int d    = 1 << (i & 7);
        int Lout = Lin - d;
        float* dst;
        int dst_stride;
        if (i == 15) { dst = out;         dst_stride = OSIZE; }
        else         { dst = bufs[i & 1]; dst_stride = L0;    }

        int W = TILE + d;
        size_t smem = (size_t)128 * W + 64 * 65 * 4 + 8 * 64 * 8 * 2;

        dim3 grid((Lout + TILE - 1) / TILE, NBATCH);
        wavenet_layer_mfma<<<grid, 256, smem, stream>>>(
            src, src_stride, Lin, dst, dst_stride,
            Wdm + (size_t)i * 64 * 128,
            Wrm + (size_t)i * 64 * 64,
            gst + (size_t)(i % G) * slotHW,
            d);

        if (((i + 1) % G) == 0) {
            dim3 sgrid((OSIZE + ST - 1) / ST, NBATCH);
            skip_gemm<<<sgrid, 256, 0, stream>>>(
                gst, Wsm, skip, G, i + 1 - G, (i + 1 == G) ? 1 : 0);
        }

        src = dst;
        src_stride = dst_stride;
        Lin = Lout;
    }
}